// Round 9
// baseline (398.596 us; speedup 1.0000x reference)
//
#include <hip/hip_runtime.h>

#define NN 50000
#define NE 1600000
#define HID 128
#define NB 196      // dst buckets: dst>>8 -> 0..195 (256 nodes each)
#define BCAP 12288  // per-bucket LDS edge capacity
#define SLH (NN * 64)  // halves per 64-col slice plane (h is [2][NN][64])

typedef _Float16 half8 __attribute__((ext_vector_type(8)));
typedef float floatx4 __attribute__((ext_vector_type(4)));
typedef unsigned int uintx4 __attribute__((ext_vector_type(4)));

// widen-accumulate: a[j] += (float)t[j] via v_fma_mix_f32 (1 instr/elem vs cvt+add)
__device__ __forceinline__ void mix_acc(float a[8], half8 t) {
  uintx4 u = __builtin_bit_cast(uintx4, t);
#pragma unroll
  for (int k = 0; k < 4; ++k) {
    asm("v_fma_mix_f32 %0, %1, %2, %0 op_sel:[0,0,0] op_sel_hi:[1,0,0]"
        : "+v"(a[2 * k]) : "v"(u[k]), "v"(1.0f));
    asm("v_fma_mix_f32 %0, %1, %2, %0 op_sel:[1,0,0] op_sel_hi:[1,0,0]"
        : "+v"(a[2 * k + 1]) : "v"(u[k]), "v"(1.0f));
  }
}

// ---------------- fused prep: cvt (fp32->fp16, SLICE-MAJOR) + pack + count ---

#define CVT_BLK 3125   // 50000*128/8 / 256
#define CNT_BLK 391    // ceil(NE/4096)

__device__ __forceinline__ void pack_one(const float* __restrict__ W1,
                                         const float* __restrict__ W2,
                                         const float* __restrict__ Wout,
                                         _Float16* __restrict__ wp, int y, int t) {
  const float* W;
  _Float16* dstp;
  int NCT;
  if (y < 3) { W = W1 + (size_t)y * 16384; dstp = wp + y * 16384; NCT = 8; }
  else if (y < 6) { W = W2 + (size_t)(y - 3) * 16384; dstp = wp + 49152 + (y - 3) * 16384; NCT = 8; }
  else { W = Wout; dstp = wp + 98304; NCT = 4; }
  if (t >= 4 * NCT * 64) return;
  int lane = t & 63;
  int ct = (t >> 6) % NCT;
  int kb = t / (64 * NCT);
  int n = ct * 16 + (lane & 15);
  int k0 = kb * 32 + (lane >> 4) * 8;
  int N = NCT * 16;
#pragma unroll
  for (int j = 0; j < 8; ++j) dstp[t * 8 + j] = (_Float16)W[(k0 + j) * N + n];
}

__global__ __launch_bounds__(256) void k_prep(
    const float* __restrict__ nf, _Float16* __restrict__ hb,
    const float* __restrict__ W1, const float* __restrict__ W2,
    const float* __restrict__ Wout, _Float16* __restrict__ wp,
    const int* __restrict__ dst, int* __restrict__ gcnt) {
  const int b = blockIdx.x;
  const int tid = threadIdx.x;
  if (b < CVT_BLK) {
    int t = b * 256 + tid;  // < 800000 exactly
    const float4* x4 = (const float4*)nf;
    float4 u = x4[t * 2], v = x4[t * 2 + 1];
    half8 o;
    o[0] = (_Float16)u.x; o[1] = (_Float16)u.y; o[2] = (_Float16)u.z; o[3] = (_Float16)u.w;
    o[4] = (_Float16)v.x; o[5] = (_Float16)v.y; o[6] = (_Float16)v.z; o[7] = (_Float16)v.w;
    int node = t >> 4, c = t & 15;
    // slice-major: hb[slice][node][64]; chunk (c&7) of 8 halves within slice c>>3
    ((half8*)hb)[(size_t)(c >> 3) * (NN * 8) + node * 8 + (c & 7)] = o;
  } else if (b < CVT_BLK + CNT_BLK) {
    __shared__ int cnt[NB];
    for (int i = tid; i < NB; i += 256) cnt[i] = 0;
    __syncthreads();
    int base = (b - CVT_BLK) * 4096;
    for (int i = 0; i < 16; ++i) {
      int e = base + i * 256 + tid;
      if (e < NE) atomicAdd(&cnt[dst[e] >> 8], 1);
    }
    __syncthreads();
    for (int i = tid; i < NB; i += 256)
      if (cnt[i]) atomicAdd(&gcnt[i], cnt[i]);
  } else {
    int bb = b - (CVT_BLK + CNT_BLK);
    pack_one(W1, W2, Wout, wp, bb >> 3, ((bb & 7) << 8) | tid);
  }
}

// ---------------- CSR build (basescan folded in; ebuf packed (src<<8)|dst&255)

// in-block exclusive scan of gcnt -> bb[0..255] (bb[i] = sum of gcnt[0..i-1])
__device__ __forceinline__ void scan_gcnt(const int* __restrict__ gcnt,
                                          int* __restrict__ bb, int tid) {
  int v = 0;
  if (tid < 256) {
    v = (tid < NB) ? gcnt[tid] : 0;
    bb[tid] = v;
  }
  __syncthreads();
  for (int d = 1; d < 256; d <<= 1) {
    int t = (tid >= d && tid < 256) ? bb[tid - d] : 0;
    __syncthreads();
    if (tid < 256) bb[tid] += t;
    __syncthreads();
  }
  int incl = (tid < 256) ? bb[tid] : 0;
  __syncthreads();
  if (tid < 256) bb[tid] = incl - v;  // exclusive
  __syncthreads();
}

__global__ __launch_bounds__(1024) void kb_partition(const int* __restrict__ src,
                                                     const int* __restrict__ dst,
                                                     const int* __restrict__ gcnt,
                                                     int* __restrict__ bcur,
                                                     int* __restrict__ ebuf, int E) {
  __shared__ int cnt[NB];
  __shared__ int sbase[NB];
  __shared__ int bb[256];
  int tid = threadIdx.x;
  scan_gcnt(gcnt, bb, tid);  // bb = bbase (bcur is a zeroed relative cursor)
  for (int i = tid; i < NB; i += 1024) cnt[i] = 0;
  __syncthreads();
  int base = blockIdx.x * 4096;
  int myd[4], mys[4];
#pragma unroll
  for (int i = 0; i < 4; ++i) {
    int e = base + i * 1024 + tid;
    if (e < E) {
      myd[i] = dst[e];
      mys[i] = src[e];
      atomicAdd(&cnt[myd[i] >> 8], 1);
    } else {
      myd[i] = -1;
    }
  }
  __syncthreads();
  for (int i = tid; i < NB; i += 1024)
    sbase[i] = cnt[i] ? (bb[i] + atomicAdd(&bcur[i], cnt[i])) : 0;
  __syncthreads();
  for (int i = tid; i < NB; i += 1024) cnt[i] = 0;
  __syncthreads();
#pragma unroll
  for (int i = 0; i < 4; ++i) {
    if (myd[i] >= 0) {
      int b = myd[i] >> 8;
      int r = atomicAdd(&cnt[b], 1);
      ebuf[sbase[b] + r] = (mys[i] << 8) | (myd[i] & 255);
    }
  }
}

__global__ __launch_bounds__(1024) void kb_csr(const int* __restrict__ ebuf,
                                               const int* __restrict__ gcnt,
                                               int* __restrict__ rs,
                                               unsigned short* __restrict__ eidx, int M) {
  __shared__ int cnt[256];
  __shared__ int off[256];
  __shared__ int bb[256];
  __shared__ int sbuf[BCAP];
  int tid = threadIdx.x;
  int b = blockIdx.x;
  scan_gcnt(gcnt, bb, tid);  // bb = bbase
  int lo = bb[b];
  int n = gcnt[b];
  if (tid < 256) cnt[tid] = 0;
  __syncthreads();
  for (int i = tid; i < n; i += 1024) atomicAdd(&cnt[ebuf[lo + i] & 255], 1);
  __syncthreads();
  int v = (tid < 256) ? cnt[tid] : 0;
  if (tid < 256) off[tid] = v;
  __syncthreads();
  for (int d = 1; d < 256; d <<= 1) {
    int t = (tid >= d && tid < 256) ? off[tid - d] : 0;
    __syncthreads();
    if (tid < 256) off[tid] += t;
    __syncthreads();
  }
  if (tid < 256) {
    int excl = off[tid] - v;
    int gnode = b * 256 + tid;
    if (gnode < M) rs[gnode] = lo + excl;
    if (b == NB - 1 && tid == 0) rs[M] = bb[NB - 1] + gcnt[NB - 1];
    cnt[tid] = excl;
  }
  __syncthreads();
  if (n <= BCAP) {
    for (int i = tid; i < n; i += 1024) {
      int ed = ebuf[lo + i];
      int r = atomicAdd(&cnt[ed & 255], 1);
      sbuf[r] = ed >> 8;
    }
    __syncthreads();
    for (int i = tid; i < n; i += 1024) eidx[lo + i] = (unsigned short)sbuf[i];
  } else {
    for (int i = tid; i < n; i += 1024) {
      int ed = ebuf[lo + i];
      int r = atomicAdd(&cnt[ed & 255], 1);
      eidx[lo + r] = (unsigned short)(ed >> 8);
    }
  }
}

// ---------------- slice-gather aggregation (2 slices x 128B rows) ------------
// AT WALL: 25.6M 16B-lane-requests / 256 CU / 2.4 GHz @ ~1/cyc/CU = 41.7 us;
// measured 43-44 us (96%). Invariant to row width (R7/R8 A/B). Do not touch.

__global__ __launch_bounds__(512, 8) void k_agg(
    const int* __restrict__ rs, const unsigned short* __restrict__ eidx,
    const float* __restrict__ eps, int layer, const _Float16* __restrict__ h,
    _Float16* __restrict__ x) {
  const int tid = threadIdx.x;
  const int b = blockIdx.x;
  const int slice = (b & 7) >> 2;              // XCD quad owns one slice
  const int tile = ((b >> 3) << 2) | (b & 3);  // 0..3127 (16-node tiles)
  const int lane = tid & 63;
  const int wid = tid >> 6;          // 0..7
  const int sub = lane & 7;          // 16B sub-chunk of 128B slice row
  const int slot = (lane >> 3) & 3;  // edge-walk slot
  const int ng = lane >> 5;          // node within wave's pair
  const int node = tile * 16 + wid * 2 + ng;
  const char* hbase = (const char*)(h + (size_t)slice * SLH);
  const unsigned subsh = (unsigned)sub << 4;

  float a[8] = {0.f, 0.f, 0.f, 0.f, 0.f, 0.f, 0.f, 0.f};
  int e0 = 0, e1 = 0;
  if (node < NN) {
    e0 = rs[node];
    e1 = rs[node + 1];
  }
  int e = e0 + slot;
  unsigned n0 = 0, n1 = 0, n2 = 0, n3 = 0;
  if (e + 12 < e1) {
    n0 = eidx[e]; n1 = eidx[e + 4]; n2 = eidx[e + 8]; n3 = eidx[e + 12];
  }
  for (; e + 12 < e1; e += 16) {
    half8 v0 = *(const half8*)(hbase + ((n0 << 7) | subsh));
    half8 v1 = *(const half8*)(hbase + ((n1 << 7) | subsh));
    half8 v2 = *(const half8*)(hbase + ((n2 << 7) | subsh));
    half8 v3 = *(const half8*)(hbase + ((n3 << 7) | subsh));
    // prefetch next iteration's indices (issued after gathers; stay in flight)
    n0 = eidx[e + 16]; n1 = eidx[e + 20]; n2 = eidx[e + 24]; n3 = eidx[e + 28];
    half8 t01 = v0 + v1;  // v_pk_add_f16 x4
    half8 t23 = v2 + v3;
    mix_acc(a, t01);
    mix_acc(a, t23);
  }
  if (e + 4 < e1) {  // 2-edge step
    unsigned s0 = eidx[e];
    unsigned s1 = eidx[e + 4];
    half8 v0 = *(const half8*)(hbase + ((s0 << 7) | subsh));
    half8 v1 = *(const half8*)(hbase + ((s1 << 7) | subsh));
    half8 t01 = v0 + v1;
    mix_acc(a, t01);
    e += 8;
  }
  for (; e < e1; e += 4) {  // tail
    unsigned s0 = eidx[e];
    half8 v = *(const half8*)(hbase + ((s0 << 7) | subsh));
    mix_acc(a, v);
  }
#pragma unroll
  for (int j = 0; j < 8; ++j) {  // reduce across the 4 slots (lane bits 3,4)
    a[j] += __shfl_xor(a[j], 8);
    a[j] += __shfl_xor(a[j], 16);
  }
  if (slot == 0 && node < NN) {
    const float ep = 1.0f + eps[layer];
    half8 hv = *(const half8*)(hbase + (((unsigned)node << 7) | subsh));
    half8 o;
#pragma unroll
    for (int j = 0; j < 8; ++j) o[j] = (_Float16)fmaf(ep, (float)hv[j], a[j]);
    *(half8*)(x + (size_t)node * 128 + slice * 64 + sub * 8) = o;
  }
}

// ---------------- BN stats only: x1 = a@W1+b1, colsum/colsumsq, NO x1 write --

__global__ __launch_bounds__(512, 8) void k_stats(
    const _Float16* __restrict__ x, const _Float16* __restrict__ wp1,
    const float* __restrict__ b1L, float* __restrict__ csum,
    float* __restrict__ csq) {
  __shared__ float sS[128];
  __shared__ float sQ[128];
  const int tid = threadIdx.x;
  const int wid = tid >> 6;
  const int lane = tid & 63;
  const int slot = lane >> 4;
  const int c8 = lane & 15;
  if (tid < 128) { sS[tid] = 0.f; sQ[tid] = 0.f; }
  __syncthreads();
  const int s = blockIdx.x * 8 + wid;
  if (s < 3125) {
    const int rowBase = s * 16;
    half8 af[4];
#pragma unroll
    for (int kb = 0; kb < 4; ++kb)
      af[kb] = *(const half8*)(x + (size_t)(rowBase + c8) * 128 + kb * 32 + slot * 8);
    const half8* wp8 = (const half8*)wp1;
    float pS[8], pQ[8];
#pragma unroll
    for (int ct = 0; ct < 8; ++ct) {
      floatx4 acc = (floatx4){0.f, 0.f, 0.f, 0.f};
#pragma unroll
      for (int kb = 0; kb < 4; ++kb)
        acc = __builtin_amdgcn_mfma_f32_16x16x32_f16(af[kb], wp8[(kb * 8 + ct) * 64 + lane],
                                                     acc, 0, 0, 0);
      float bv = b1L[ct * 16 + c8];
      float ps = 0.f, pq = 0.f;
#pragma unroll
      for (int reg = 0; reg < 4; ++reg) {
        float xv = acc[reg] + bv;
        ps += xv;
        pq += xv * xv;
      }
      ps += __shfl_xor(ps, 16);
      ps += __shfl_xor(ps, 32);
      pq += __shfl_xor(pq, 16);
      pq += __shfl_xor(pq, 32);
      pS[ct] = ps;
      pQ[ct] = pq;
    }
    if (lane < 16) {
#pragma unroll
      for (int ct = 0; ct < 8; ++ct) {
        atomicAdd(&sS[ct * 16 + c8], pS[ct]);
        atomicAdd(&sQ[ct * 16 + c8], pQ[ct]);
      }
    }
  }
  __syncthreads();
  if (tid < 128) atomicAdd(&csum[tid], sS[tid]);
  else if (tid < 256) atomicAdd(&csq[tid - 128], sQ[tid - 128]);
}

// ---------------- fused GEMM1-recompute + BN + GEMM2 (+ Wout when FINAL) ----
// R9: 391 blocks x 2 sequential row-tiles. 782x16-wave blocks = 1.53 dispatch
// rounds (2nd round 53% empty); 391 blocks = 0.76 rounds, one clean pass.
// BN-constant loads amortized across both tiles.

template <int FINAL>
__global__ __launch_bounds__(1024, 8) void k_bngemm12(
    const _Float16* __restrict__ x, const _Float16* __restrict__ wp1,
    const float* __restrict__ b1L, const _Float16* __restrict__ wp2,
    const float* __restrict__ b2L, const float* __restrict__ gammaL,
    const float* __restrict__ betaL, const float* __restrict__ csum,
    const float* __restrict__ csq, _Float16* __restrict__ hout,
    const _Float16* __restrict__ wpo, const float* __restrict__ boutp,
    float* __restrict__ out) {
  __shared__ _Float16 As[64 * 136];
  const int tid = threadIdx.x;
  const int wid = tid >> 6;
  const int lane = tid & 63;
  const int slot = lane >> 4;
  const int c8 = lane & 15;
  const int c8t = tid & 15;
  const int rg = wid & 3;
  const int cg = wid >> 2;

  // per-lane BN constants for its two output col-tiles (b1 folded into shift)
  float sc_t[2], sh_t[2];
  {
    const float invM = 1.0f / (float)NN;
#pragma unroll
    for (int t = 0; t < 2; ++t) {
      int k = (cg * 2 + t) * 16 + c8;
      float mu = csum[k] * invM;
      float var = csq[k] * invM - mu * mu;
      float g = gammaL[k] * rsqrtf(var + 1e-5f);
      sc_t[t] = g;
      sh_t[t] = fmaf(b1L[k] - mu, g, betaL[k]);
    }
  }

  for (int tt = 0; tt < 2; ++tt) {
    const int rowBase = (blockIdx.x * 2 + tt) * 64;
    __syncthreads();  // protect As reuse across iterations
    // stage a-tile (rows >= NN zeroed)
    {
      int row = tid >> 4;
      int gr = rowBase + row;
      half8 v = {0, 0, 0, 0, 0, 0, 0, 0};
      if (gr < NN) v = *(const half8*)(x + (size_t)gr * 128 + c8t * 8);
      *(half8*)(As + row * 136 + c8t * 8) = v;
    }
    __syncthreads();

    // GEMM1
    floatx4 acc[2];
    acc[0] = (floatx4){0.f, 0.f, 0.f, 0.f};
    acc[1] = (floatx4){0.f, 0.f, 0.f, 0.f};
    {
      const half8* wp8 = (const half8*)wp1;
#pragma unroll
      for (int kb = 0; kb < 4; ++kb) {
        half8 a = *(const half8*)(As + (rg * 16 + c8) * 136 + kb * 32 + slot * 8);
#pragma unroll
        for (int t = 0; t < 2; ++t) {
          int ct = cg * 2 + t;
          acc[t] = __builtin_amdgcn_mfma_f32_16x16x32_f16(
              a, wp8[(kb * 8 + ct) * 64 + lane], acc[t], 0, 0, 0);
        }
      }
    }
    __syncthreads();
    // y = relu(BN(x1)) -> As
#pragma unroll
    for (int t = 0; t < 2; ++t) {
      int ct = cg * 2 + t;
#pragma unroll
      for (int reg = 0; reg < 4; ++reg) {
        int row = rg * 16 + slot * 4 + reg;
        As[row * 136 + ct * 16 + c8] =
            (_Float16)fmaxf(fmaf(acc[t][reg], sc_t[t], sh_t[t]), 0.f);
      }
    }
    __syncthreads();

    // GEMM2
    acc[0] = (floatx4){0.f, 0.f, 0.f, 0.f};
    acc[1] = (floatx4){0.f, 0.f, 0.f, 0.f};
    {
      const half8* wp8 = (const half8*)wp2;
#pragma unroll
      for (int kb = 0; kb < 4; ++kb) {
        half8 a = *(const half8*)(As + (rg * 16 + c8) * 136 + kb * 32 + slot * 8);
#pragma unroll
        for (int t = 0; t < 2; ++t) {
          int ct = cg * 2 + t;
          acc[t] = __builtin_amdgcn_mfma_f32_16x16x32_f16(
              a, wp8[(kb * 8 + ct) * 64 + lane], acc[t], 0, 0, 0);
        }
      }
    }
    __syncthreads();
#pragma unroll
    for (int t = 0; t < 2; ++t) {
      int ct = cg * 2 + t;
      float bv = b2L[ct * 16 + c8];
#pragma unroll
      for (int reg = 0; reg < 4; ++reg) {
        int row = rg * 16 + slot * 4 + reg;
        As[row * 136 + ct * 16 + c8] = (_Float16)fmaxf(acc[t][reg] + bv, 0.f);
      }
    }
    __syncthreads();

    if (FINAL == 0) {
      int row = tid >> 4;
      int gr = rowBase + row;
      if (gr < NN) {
        half8 v = *(half8*)(As + row * 136 + c8t * 8);
        // slice-major [2][NN][64] for next layer's gather
        *(half8*)(hout + (size_t)(c8t >> 3) * SLH + (size_t)gr * 64 + (c8t & 7) * 8) = v;
      }
    } else {
      if (cg < 2) {
        floatx4 acc3[2];
        acc3[0] = (floatx4){0.f, 0.f, 0.f, 0.f};
        acc3[1] = (floatx4){0.f, 0.f, 0.f, 0.f};
        const half8* wo8 = (const half8*)wpo;
#pragma unroll
        for (int kb = 0; kb < 4; ++kb) {
          half8 a = *(const half8*)(As + (rg * 16 + c8) * 136 + kb * 32 + slot * 8);
#pragma unroll
          for (int t = 0; t < 2; ++t) {
            int ct = cg * 2 + t;
            acc3[t] = __builtin_amdgcn_mfma_f32_16x16x32_f16(
                a, wo8[(kb * 4 + ct) * 64 + lane], acc3[t], 0, 0, 0);
          }
        }
#pragma unroll
        for (int t = 0; t < 2; ++t) {
          int ct = cg * 2 + t;
          float bv = boutp[ct * 16 + c8];
#pragma unroll
          for (int reg = 0; reg < 4; ++reg) {
            int gr = rowBase + rg * 16 + slot * 4 + reg;
            if (gr < NN) out[(size_t)gr * 64 + ct * 16 + c8] = acc3[t][reg] + bv;
          }
        }
      }
    }
  }
}

// ---------------- launch ----------------

extern "C" void kernel_launch(void* const* d_in, const int* in_sizes, int n_in,
                              void* d_out, int out_size, void* d_ws, size_t ws_size,
                              hipStream_t stream) {
  const float* node_feat = (const float*)d_in[0];
  const int* src = (const int*)d_in[1];
  const int* dst = (const int*)d_in[2];
  const float* W1 = (const float*)d_in[3];
  const float* b1 = (const float*)d_in[4];
  const float* gamma = (const float*)d_in[5];
  const float* beta = (const float*)d_in[6];
  const float* W2 = (const float*)d_in[7];
  const float* b2 = (const float*)d_in[8];
  const float* eps = (const float*)d_in[9];
  const float* Wout = (const float*)d_in[10];
  const float* bout = (const float*)d_in[11];
  float* out = (float*)d_out;

  // workspace layout (16B-aligned slices) — unchanged footprint
  int* rs = (int*)d_ws;                  // 50176 ints
  int* gcnt = rs + 50176;                // 256
  int* bbase = gcnt + 256;               // 256 (unused, kept for layout)
  int* bcur = bbase + 256;               // 256 (zeroed relative cursors)
  float* stats = (float*)(bcur + 256);   // 768 floats: 3 x (csum|csq)
  int* eidx = (int*)(stats + 768);       // NE-int region, used as u16
  _Float16* hb = (_Float16*)(eidx + NE);      // h, slice-major [2][NN][64]
  _Float16* xb = hb + (size_t)NN * HID;       // a, row-major [NN][128]
  _Float16* wp = xb + (size_t)NN * HID;       // packed weights (106496 halves)
  int* ebuf = (int*)(wp + 106496);            // NE packed ints staging

  unsigned short* eidx16 = (unsigned short*)eidx;

  hipMemsetAsync(gcnt, 0, (256 * 3 + 768) * sizeof(int), stream);

  // fused cvt + count + pack
  k_prep<<<CVT_BLK + CNT_BLK + 56, 256, 0, stream>>>(node_feat, hb, W1, W2, Wout,
                                                     wp, dst, gcnt);
  kb_partition<<<CNT_BLK, 1024, 0, stream>>>(src, dst, gcnt, bcur, ebuf, NE);
  kb_csr<<<NB, 1024, 0, stream>>>(ebuf, gcnt, rs, eidx16, NN);

  const int aggBlocks = 782 * 8;  // 6256: (slice, 16-node tile) via blockIdx%8

  for (int L = 0; L < 3; ++L) {
    float* csum = stats + L * 256;
    float* csq = csum + 128;
    k_agg<<<aggBlocks, 512, 0, stream>>>(rs, eidx16, eps, L, hb, xb);
    k_stats<<<391, 512, 0, stream>>>(xb, wp + (size_t)L * 16384,
                                     b1 + (size_t)L * HID, csum, csq);
    if (L < 2) {
      k_bngemm12<0><<<391, 1024, 0, stream>>>(
          xb, wp + (size_t)L * 16384, b1 + (size_t)L * HID,
          wp + 49152 + (size_t)L * 16384, b2 + (size_t)L * HID,
          gamma + (size_t)L * HID, beta + (size_t)L * HID, csum, csq, hb,
          nullptr, nullptr, nullptr);
    } else {
      k_bngemm12<1><<<391, 1024, 0, stream>>>(
          xb, wp + (size_t)L * 16384, b1 + (size_t)L * HID,
          wp + 49152 + (size_t)L * 16384, b2 + (size_t)L * HID,
          gamma + (size_t)L * HID, beta + (size_t)L * HID, csum, csq, nullptr,
          wp + 98304, bout, out);
    }
  }
}

// Round 10
// 362.941 us; speedup vs baseline: 1.0982x; 1.0982x over previous
//
#include <hip/hip_runtime.h>

#define NN 50000
#define NE 1600000
#define HID 128
#define NB 196      // dst buckets: dst>>8 -> 0..195 (256 nodes each)
#define BCAP 12288  // per-bucket LDS edge capacity
#define SLH (NN * 64)  // halves per 64-col slice plane (h is [2][NN][64])

typedef _Float16 half8 __attribute__((ext_vector_type(8)));
typedef float floatx4 __attribute__((ext_vector_type(4)));
typedef unsigned int uintx4 __attribute__((ext_vector_type(4)));

// widen-accumulate: a[j] += (float)t[j] via v_fma_mix_f32 (1 instr/elem vs cvt+add)
__device__ __forceinline__ void mix_acc(float a[8], half8 t) {
  uintx4 u = __builtin_bit_cast(uintx4, t);
#pragma unroll
  for (int k = 0; k < 4; ++k) {
    asm("v_fma_mix_f32 %0, %1, %2, %0 op_sel:[0,0,0] op_sel_hi:[1,0,0]"
        : "+v"(a[2 * k]) : "v"(u[k]), "v"(1.0f));
    asm("v_fma_mix_f32 %0, %1, %2, %0 op_sel:[1,0,0] op_sel_hi:[1,0,0]"
        : "+v"(a[2 * k + 1]) : "v"(u[k]), "v"(1.0f));
  }
}

// ---------------- fused prep: cvt (fp32->fp16, SLICE-MAJOR) + pack + count ---

#define CVT_BLK 3125   // 50000*128/8 / 256
#define CNT_BLK 391    // ceil(NE/4096)

__device__ __forceinline__ void pack_one(const float* __restrict__ W1,
                                         const float* __restrict__ W2,
                                         const float* __restrict__ Wout,
                                         _Float16* __restrict__ wp, int y, int t) {
  const float* W;
  _Float16* dstp;
  int NCT;
  if (y < 3) { W = W1 + (size_t)y * 16384; dstp = wp + y * 16384; NCT = 8; }
  else if (y < 6) { W = W2 + (size_t)(y - 3) * 16384; dstp = wp + 49152 + (y - 3) * 16384; NCT = 8; }
  else { W = Wout; dstp = wp + 98304; NCT = 4; }
  if (t >= 4 * NCT * 64) return;
  int lane = t & 63;
  int ct = (t >> 6) % NCT;
  int kb = t / (64 * NCT);
  int n = ct * 16 + (lane & 15);
  int k0 = kb * 32 + (lane >> 4) * 8;
  int N = NCT * 16;
#pragma unroll
  for (int j = 0; j < 8; ++j) dstp[t * 8 + j] = (_Float16)W[(k0 + j) * N + n];
}

__global__ __launch_bounds__(256) void k_prep(
    const float* __restrict__ nf, _Float16* __restrict__ hb,
    const float* __restrict__ W1, const float* __restrict__ W2,
    const float* __restrict__ Wout, _Float16* __restrict__ wp,
    const int* __restrict__ dst, int* __restrict__ gcnt) {
  const int b = blockIdx.x;
  const int tid = threadIdx.x;
  if (b < CVT_BLK) {
    int t = b * 256 + tid;  // < 800000 exactly
    const float4* x4 = (const float4*)nf;
    float4 u = x4[t * 2], v = x4[t * 2 + 1];
    half8 o;
    o[0] = (_Float16)u.x; o[1] = (_Float16)u.y; o[2] = (_Float16)u.z; o[3] = (_Float16)u.w;
    o[4] = (_Float16)v.x; o[5] = (_Float16)v.y; o[6] = (_Float16)v.z; o[7] = (_Float16)v.w;
    int node = t >> 4, c = t & 15;
    // slice-major: hb[slice][node][64]; chunk (c&7) of 8 halves within slice c>>3
    ((half8*)hb)[(size_t)(c >> 3) * (NN * 8) + node * 8 + (c & 7)] = o;
  } else if (b < CVT_BLK + CNT_BLK) {
    __shared__ int cnt[NB];
    for (int i = tid; i < NB; i += 256) cnt[i] = 0;
    __syncthreads();
    int base = (b - CVT_BLK) * 4096;
    for (int i = 0; i < 16; ++i) {
      int e = base + i * 256 + tid;
      if (e < NE) atomicAdd(&cnt[dst[e] >> 8], 1);
    }
    __syncthreads();
    for (int i = tid; i < NB; i += 256)
      if (cnt[i]) atomicAdd(&gcnt[i], cnt[i]);
  } else {
    int bb = b - (CVT_BLK + CNT_BLK);
    pack_one(W1, W2, Wout, wp, bb >> 3, ((bb & 7) << 8) | tid);
  }
}

// ---------------- CSR build (basescan folded in; ebuf packed (src<<8)|dst&255)

// in-block exclusive scan of gcnt -> bb[0..255] (bb[i] = sum of gcnt[0..i-1])
__device__ __forceinline__ void scan_gcnt(const int* __restrict__ gcnt,
                                          int* __restrict__ bb, int tid) {
  int v = 0;
  if (tid < 256) {
    v = (tid < NB) ? gcnt[tid] : 0;
    bb[tid] = v;
  }
  __syncthreads();
  for (int d = 1; d < 256; d <<= 1) {
    int t = (tid >= d && tid < 256) ? bb[tid - d] : 0;
    __syncthreads();
    if (tid < 256) bb[tid] += t;
    __syncthreads();
  }
  int incl = (tid < 256) ? bb[tid] : 0;
  __syncthreads();
  if (tid < 256) bb[tid] = incl - v;  // exclusive
  __syncthreads();
}

__global__ __launch_bounds__(1024) void kb_partition(const int* __restrict__ src,
                                                     const int* __restrict__ dst,
                                                     const int* __restrict__ gcnt,
                                                     int* __restrict__ bcur,
                                                     int* __restrict__ ebuf, int E) {
  __shared__ int cnt[NB];
  __shared__ int sbase[NB];
  __shared__ int bb[256];
  int tid = threadIdx.x;
  scan_gcnt(gcnt, bb, tid);  // bb = bbase (bcur is a zeroed relative cursor)
  for (int i = tid; i < NB; i += 1024) cnt[i] = 0;
  __syncthreads();
  int base = blockIdx.x * 4096;
  int myd[4], mys[4];
#pragma unroll
  for (int i = 0; i < 4; ++i) {
    int e = base + i * 1024 + tid;
    if (e < E) {
      myd[i] = dst[e];
      mys[i] = src[e];
      atomicAdd(&cnt[myd[i] >> 8], 1);
    } else {
      myd[i] = -1;
    }
  }
  __syncthreads();
  for (int i = tid; i < NB; i += 1024)
    sbase[i] = cnt[i] ? (bb[i] + atomicAdd(&bcur[i], cnt[i])) : 0;
  __syncthreads();
  for (int i = tid; i < NB; i += 1024) cnt[i] = 0;
  __syncthreads();
#pragma unroll
  for (int i = 0; i < 4; ++i) {
    if (myd[i] >= 0) {
      int b = myd[i] >> 8;
      int r = atomicAdd(&cnt[b], 1);
      ebuf[sbase[b] + r] = (mys[i] << 8) | (myd[i] & 255);
    }
  }
}

__global__ __launch_bounds__(1024) void kb_csr(const int* __restrict__ ebuf,
                                               const int* __restrict__ gcnt,
                                               int* __restrict__ rs,
                                               unsigned short* __restrict__ eidx, int M) {
  __shared__ int cnt[256];
  __shared__ int off[256];
  __shared__ int bb[256];
  __shared__ int sbuf[BCAP];
  int tid = threadIdx.x;
  int b = blockIdx.x;
  scan_gcnt(gcnt, bb, tid);  // bb = bbase
  int lo = bb[b];
  int n = gcnt[b];
  if (tid < 256) cnt[tid] = 0;
  __syncthreads();
  for (int i = tid; i < n; i += 1024) atomicAdd(&cnt[ebuf[lo + i] & 255], 1);
  __syncthreads();
  int v = (tid < 256) ? cnt[tid] : 0;
  if (tid < 256) off[tid] = v;
  __syncthreads();
  for (int d = 1; d < 256; d <<= 1) {
    int t = (tid >= d && tid < 256) ? off[tid - d] : 0;
    __syncthreads();
    if (tid < 256) off[tid] += t;
    __syncthreads();
  }
  if (tid < 256) {
    int excl = off[tid] - v;
    int gnode = b * 256 + tid;
    if (gnode < M) rs[gnode] = lo + excl;
    if (b == NB - 1 && tid == 0) rs[M] = bb[NB - 1] + gcnt[NB - 1];
    cnt[tid] = excl;
  }
  __syncthreads();
  if (n <= BCAP) {
    for (int i = tid; i < n; i += 1024) {
      int ed = ebuf[lo + i];
      int r = atomicAdd(&cnt[ed & 255], 1);
      sbuf[r] = ed >> 8;
    }
    __syncthreads();
    for (int i = tid; i < n; i += 1024) eidx[lo + i] = (unsigned short)sbuf[i];
  } else {
    for (int i = tid; i < n; i += 1024) {
      int ed = ebuf[lo + i];
      int r = atomicAdd(&cnt[ed & 255], 1);
      eidx[lo + r] = (unsigned short)(ed >> 8);
    }
  }
}

// ---------------- slice-gather aggregation (2 slices x 128B rows) ------------
// AT WALL: 25.6M 16B-lane-requests / 256 CU / 2.4 GHz @ ~1/cyc/CU = 41.7 us;
// measured 43-44 us (96%). Invariant to row width (R7/R8 A/B). Do not touch.

__global__ __launch_bounds__(512, 8) void k_agg(
    const int* __restrict__ rs, const unsigned short* __restrict__ eidx,
    const float* __restrict__ eps, int layer, const _Float16* __restrict__ h,
    _Float16* __restrict__ x) {
  const int tid = threadIdx.x;
  const int b = blockIdx.x;
  const int slice = (b & 7) >> 2;              // XCD quad owns one slice
  const int tile = ((b >> 3) << 2) | (b & 3);  // 0..3127 (16-node tiles)
  const int lane = tid & 63;
  const int wid = tid >> 6;          // 0..7
  const int sub = lane & 7;          // 16B sub-chunk of 128B slice row
  const int slot = (lane >> 3) & 3;  // edge-walk slot
  const int ng = lane >> 5;          // node within wave's pair
  const int node = tile * 16 + wid * 2 + ng;
  const char* hbase = (const char*)(h + (size_t)slice * SLH);
  const unsigned subsh = (unsigned)sub << 4;

  float a[8] = {0.f, 0.f, 0.f, 0.f, 0.f, 0.f, 0.f, 0.f};
  int e0 = 0, e1 = 0;
  if (node < NN) {
    e0 = rs[node];
    e1 = rs[node + 1];
  }
  int e = e0 + slot;
  unsigned n0 = 0, n1 = 0, n2 = 0, n3 = 0;
  if (e + 12 < e1) {
    n0 = eidx[e]; n1 = eidx[e + 4]; n2 = eidx[e + 8]; n3 = eidx[e + 12];
  }
  for (; e + 12 < e1; e += 16) {
    half8 v0 = *(const half8*)(hbase + ((n0 << 7) | subsh));
    half8 v1 = *(const half8*)(hbase + ((n1 << 7) | subsh));
    half8 v2 = *(const half8*)(hbase + ((n2 << 7) | subsh));
    half8 v3 = *(const half8*)(hbase + ((n3 << 7) | subsh));
    // prefetch next iteration's indices (issued after gathers; stay in flight)
    n0 = eidx[e + 16]; n1 = eidx[e + 20]; n2 = eidx[e + 24]; n3 = eidx[e + 28];
    half8 t01 = v0 + v1;  // v_pk_add_f16 x4
    half8 t23 = v2 + v3;
    mix_acc(a, t01);
    mix_acc(a, t23);
  }
  if (e + 4 < e1) {  // 2-edge step
    unsigned s0 = eidx[e];
    unsigned s1 = eidx[e + 4];
    half8 v0 = *(const half8*)(hbase + ((s0 << 7) | subsh));
    half8 v1 = *(const half8*)(hbase + ((s1 << 7) | subsh));
    half8 t01 = v0 + v1;
    mix_acc(a, t01);
    e += 8;
  }
  for (; e < e1; e += 4) {  // tail
    unsigned s0 = eidx[e];
    half8 v = *(const half8*)(hbase + ((s0 << 7) | subsh));
    mix_acc(a, v);
  }
#pragma unroll
  for (int j = 0; j < 8; ++j) {  // reduce across the 4 slots (lane bits 3,4)
    a[j] += __shfl_xor(a[j], 8);
    a[j] += __shfl_xor(a[j], 16);
  }
  if (slot == 0 && node < NN) {
    const float ep = 1.0f + eps[layer];
    half8 hv = *(const half8*)(hbase + (((unsigned)node << 7) | subsh));
    half8 o;
#pragma unroll
    for (int j = 0; j < 8; ++j) o[j] = (_Float16)fmaf(ep, (float)hv[j], a[j]);
    *(half8*)(x + (size_t)node * 128 + slice * 64 + sub * 8) = o;
  }
}

// ---------------- BN stats only: x1 = a@W1+b1, colsum/colsumsq, NO x1 write --

__global__ __launch_bounds__(512, 8) void k_stats(
    const _Float16* __restrict__ x, const _Float16* __restrict__ wp1,
    const float* __restrict__ b1L, float* __restrict__ csum,
    float* __restrict__ csq) {
  __shared__ float sS[128];
  __shared__ float sQ[128];
  const int tid = threadIdx.x;
  const int wid = tid >> 6;
  const int lane = tid & 63;
  const int slot = lane >> 4;
  const int c8 = lane & 15;
  if (tid < 128) { sS[tid] = 0.f; sQ[tid] = 0.f; }
  __syncthreads();
  const int s = blockIdx.x * 8 + wid;
  if (s < 3125) {
    const int rowBase = s * 16;
    half8 af[4];
#pragma unroll
    for (int kb = 0; kb < 4; ++kb)
      af[kb] = *(const half8*)(x + (size_t)(rowBase + c8) * 128 + kb * 32 + slot * 8);
    const half8* wp8 = (const half8*)wp1;
    float pS[8], pQ[8];
#pragma unroll
    for (int ct = 0; ct < 8; ++ct) {
      floatx4 acc = (floatx4){0.f, 0.f, 0.f, 0.f};
#pragma unroll
      for (int kb = 0; kb < 4; ++kb)
        acc = __builtin_amdgcn_mfma_f32_16x16x32_f16(af[kb], wp8[(kb * 8 + ct) * 64 + lane],
                                                     acc, 0, 0, 0);
      float bv = b1L[ct * 16 + c8];
      float ps = 0.f, pq = 0.f;
#pragma unroll
      for (int reg = 0; reg < 4; ++reg) {
        float xv = acc[reg] + bv;
        ps += xv;
        pq += xv * xv;
      }
      ps += __shfl_xor(ps, 16);
      ps += __shfl_xor(ps, 32);
      pq += __shfl_xor(pq, 16);
      pq += __shfl_xor(pq, 32);
      pS[ct] = ps;
      pQ[ct] = pq;
    }
    if (lane < 16) {
#pragma unroll
      for (int ct = 0; ct < 8; ++ct) {
        atomicAdd(&sS[ct * 16 + c8], pS[ct]);
        atomicAdd(&sQ[ct * 16 + c8], pQ[ct]);
      }
    }
  }
  __syncthreads();
  if (tid < 128) atomicAdd(&csum[tid], sS[tid]);
  else if (tid < 256) atomicAdd(&csq[tid - 128], sQ[tid - 128]);
}

// ---------------- fused GEMM1-recompute + BN + GEMM2 (+ Wout when FINAL) ----
// R8-verified shape: 782 blocks x ONE 64-row tile. (R9's 391x2 regressed:
// fewer/longer blocks coarsen per-CU load balancing — 1.53 long blocks/CU
// quantizes worse than 3.05 short ones.)

template <int FINAL>
__global__ __launch_bounds__(1024, 8) void k_bngemm12(
    const _Float16* __restrict__ x, const _Float16* __restrict__ wp1,
    const float* __restrict__ b1L, const _Float16* __restrict__ wp2,
    const float* __restrict__ b2L, const float* __restrict__ gammaL,
    const float* __restrict__ betaL, const float* __restrict__ csum,
    const float* __restrict__ csq, _Float16* __restrict__ hout,
    const _Float16* __restrict__ wpo, const float* __restrict__ boutp,
    float* __restrict__ out) {
  __shared__ _Float16 As[64 * 136];
  const int tid = threadIdx.x;
  const int wid = tid >> 6;
  const int lane = tid & 63;
  const int slot = lane >> 4;
  const int c8 = lane & 15;
  const int c8t = tid & 15;
  const int rowBase = blockIdx.x * 64;
  const int rg = wid & 3;
  const int cg = wid >> 2;

  // per-lane BN constants for its two output col-tiles (b1 folded into shift)
  float sc_t[2], sh_t[2];
  {
    const float invM = 1.0f / (float)NN;
#pragma unroll
    for (int t = 0; t < 2; ++t) {
      int k = (cg * 2 + t) * 16 + c8;
      float mu = csum[k] * invM;
      float var = csq[k] * invM - mu * mu;
      float g = gammaL[k] * rsqrtf(var + 1e-5f);
      sc_t[t] = g;
      sh_t[t] = fmaf(b1L[k] - mu, g, betaL[k]);
    }
  }
  // stage a-tile (rows >= NN zeroed)
  {
    int row = tid >> 4;
    int gr = rowBase + row;
    half8 v = {0, 0, 0, 0, 0, 0, 0, 0};
    if (gr < NN) v = *(const half8*)(x + (size_t)gr * 128 + c8t * 8);
    *(half8*)(As + row * 136 + c8t * 8) = v;
  }
  __syncthreads();

  // GEMM1
  floatx4 acc[2];
  acc[0] = (floatx4){0.f, 0.f, 0.f, 0.f};
  acc[1] = (floatx4){0.f, 0.f, 0.f, 0.f};
  {
    const half8* wp8 = (const half8*)wp1;
#pragma unroll
    for (int kb = 0; kb < 4; ++kb) {
      half8 a = *(const half8*)(As + (rg * 16 + c8) * 136 + kb * 32 + slot * 8);
#pragma unroll
      for (int t = 0; t < 2; ++t) {
        int ct = cg * 2 + t;
        acc[t] = __builtin_amdgcn_mfma_f32_16x16x32_f16(a, wp8[(kb * 8 + ct) * 64 + lane],
                                                        acc[t], 0, 0, 0);
      }
    }
  }
  __syncthreads();
  // y = relu(BN(x1)) -> As
#pragma unroll
  for (int t = 0; t < 2; ++t) {
    int ct = cg * 2 + t;
#pragma unroll
    for (int reg = 0; reg < 4; ++reg) {
      int row = rg * 16 + slot * 4 + reg;
      As[row * 136 + ct * 16 + c8] =
          (_Float16)fmaxf(fmaf(acc[t][reg], sc_t[t], sh_t[t]), 0.f);
    }
  }
  __syncthreads();

  // GEMM2
  acc[0] = (floatx4){0.f, 0.f, 0.f, 0.f};
  acc[1] = (floatx4){0.f, 0.f, 0.f, 0.f};
  {
    const half8* wp8 = (const half8*)wp2;
#pragma unroll
    for (int kb = 0; kb < 4; ++kb) {
      half8 a = *(const half8*)(As + (rg * 16 + c8) * 136 + kb * 32 + slot * 8);
#pragma unroll
      for (int t = 0; t < 2; ++t) {
        int ct = cg * 2 + t;
        acc[t] = __builtin_amdgcn_mfma_f32_16x16x32_f16(a, wp8[(kb * 8 + ct) * 64 + lane],
                                                        acc[t], 0, 0, 0);
      }
    }
  }
  __syncthreads();
#pragma unroll
  for (int t = 0; t < 2; ++t) {
    int ct = cg * 2 + t;
    float bv = b2L[ct * 16 + c8];
#pragma unroll
    for (int reg = 0; reg < 4; ++reg) {
      int row = rg * 16 + slot * 4 + reg;
      As[row * 136 + ct * 16 + c8] = (_Float16)fmaxf(acc[t][reg] + bv, 0.f);
    }
  }
  __syncthreads();

  if (FINAL == 0) {
    int row = tid >> 4;
    int gr = rowBase + row;
    if (gr < NN) {
      half8 v = *(half8*)(As + row * 136 + c8t * 8);
      // slice-major [2][NN][64] for next layer's gather
      *(half8*)(hout + (size_t)(c8t >> 3) * SLH + (size_t)gr * 64 + (c8t & 7) * 8) = v;
    }
  } else {
    if (cg < 2) {
      floatx4 acc3[2];
      acc3[0] = (floatx4){0.f, 0.f, 0.f, 0.f};
      acc3[1] = (floatx4){0.f, 0.f, 0.f, 0.f};
      const half8* wo8 = (const half8*)wpo;
#pragma unroll
      for (int kb = 0; kb < 4; ++kb) {
        half8 a = *(const half8*)(As + (rg * 16 + c8) * 136 + kb * 32 + slot * 8);
#pragma unroll
        for (int t = 0; t < 2; ++t) {
          int ct = cg * 2 + t;
          acc3[t] = __builtin_amdgcn_mfma_f32_16x16x32_f16(
              a, wo8[(kb * 4 + ct) * 64 + lane], acc3[t], 0, 0, 0);
        }
      }
#pragma unroll
      for (int t = 0; t < 2; ++t) {
        int ct = cg * 2 + t;
        float bv = boutp[ct * 16 + c8];
#pragma unroll
        for (int reg = 0; reg < 4; ++reg) {
          int gr = rowBase + rg * 16 + slot * 4 + reg;
          if (gr < NN) out[(size_t)gr * 64 + ct * 16 + c8] = acc3[t][reg] + bv;
        }
      }
    }
  }
}

// ---------------- launch ----------------

extern "C" void kernel_launch(void* const* d_in, const int* in_sizes, int n_in,
                              void* d_out, int out_size, void* d_ws, size_t ws_size,
                              hipStream_t stream) {
  const float* node_feat = (const float*)d_in[0];
  const int* src = (const int*)d_in[1];
  const int* dst = (const int*)d_in[2];
  const float* W1 = (const float*)d_in[3];
  const float* b1 = (const float*)d_in[4];
  const float* gamma = (const float*)d_in[5];
  const float* beta = (const float*)d_in[6];
  const float* W2 = (const float*)d_in[7];
  const float* b2 = (const float*)d_in[8];
  const float* eps = (const float*)d_in[9];
  const float* Wout = (const float*)d_in[10];
  const float* bout = (const float*)d_in[11];
  float* out = (float*)d_out;

  // workspace layout (16B-aligned slices) — unchanged footprint
  int* rs = (int*)d_ws;                  // 50176 ints
  int* gcnt = rs + 50176;                // 256
  int* bbase = gcnt + 256;               // 256 (unused, kept for layout)
  int* bcur = bbase + 256;               // 256 (zeroed relative cursors)
  float* stats = (float*)(bcur + 256);   // 768 floats: 3 x (csum|csq)
  int* eidx = (int*)(stats + 768);       // NE-int region, used as u16
  _Float16* hb = (_Float16*)(eidx + NE);      // h, slice-major [2][NN][64]
  _Float16* xb = hb + (size_t)NN * HID;       // a, row-major [NN][128]
  _Float16* wp = xb + (size_t)NN * HID;       // packed weights (106496 halves)
  int* ebuf = (int*)(wp + 106496);            // NE packed ints staging

  unsigned short* eidx16 = (unsigned short*)eidx;

  hipMemsetAsync(gcnt, 0, (256 * 3 + 768) * sizeof(int), stream);

  // fused cvt + count + pack
  k_prep<<<CVT_BLK + CNT_BLK + 56, 256, 0, stream>>>(node_feat, hb, W1, W2, Wout,
                                                     wp, dst, gcnt);
  kb_partition<<<CNT_BLK, 1024, 0, stream>>>(src, dst, gcnt, bcur, ebuf, NE);
  kb_csr<<<NB, 1024, 0, stream>>>(ebuf, gcnt, rs, eidx16, NN);

  const int rowTiles = (NN + 63) / 64;  // 782
  const int aggBlocks = 782 * 8;        // 6256: (slice, 16-node tile) via blockIdx%8

  for (int L = 0; L < 3; ++L) {
    float* csum = stats + L * 256;
    float* csq = csum + 128;
    k_agg<<<aggBlocks, 512, 0, stream>>>(rs, eidx16, eps, L, hb, xb);
    k_stats<<<391, 512, 0, stream>>>(xb, wp + (size_t)L * 16384,
                                     b1 + (size_t)L * HID, csum, csq);
    if (L < 2) {
      k_bngemm12<0><<<rowTiles, 1024, 0, stream>>>(
          xb, wp + (size_t)L * 16384, b1 + (size_t)L * HID,
          wp + 49152 + (size_t)L * 16384, b2 + (size_t)L * HID,
          gamma + (size_t)L * HID, beta + (size_t)L * HID, csum, csq, hb,
          nullptr, nullptr, nullptr);
    } else {
      k_bngemm12<1><<<rowTiles, 1024, 0, stream>>>(
          xb, wp + (size_t)L * 16384, b1 + (size_t)L * HID,
          wp + 49152 + (size_t)L * 16384, b2 + (size_t)L * HID,
          gamma + (size_t)L * HID, beta + (size_t)L * HID, csum, csq, nullptr,
          wp + 98304, bout, out);
    }
  }
}